// Round 1
// baseline (4817.596 us; speedup 1.0000x reference)
//
#include <hip/hip_runtime.h>
#include <math.h>

// Problem dims (fixed by the reference file)
#define DHID 128
#define DXIN 16
#define DIN  144   // DHID + DXIN
#define G3   384   // 3*DHID
#define NLEV 16

__device__ __forceinline__ float sigmoidf_(float v){ return 1.0f/(1.0f + __expf(-v)); }

// ---------------- zero workspace (msg buffer + counters) ----------------
__global__ void k_zero(float* msgC, long long n4, int* ints, int nints){
  long long i = (long long)blockIdx.x*blockDim.x + threadIdx.x;
  long long stride = (long long)gridDim.x*blockDim.x;
  float4 z = make_float4(0.f,0.f,0.f,0.f);
  float4* m4 = (float4*)msgC;
  for(long long j=i;j<n4;j+=stride) m4[j]=z;
  if(i<nints) ints[i]=0;
}

// ---------------- precompute h_init, t_init, gh_init, c0 ----------------
// consts layout (floats): [0..127]=h_init [128..255]=t_init [256..639]=gh_init [640]=c0
__global__ void k_init(const float* emd_w, const float* emd_b,
                       const float* agg_w, const float* agg_b,
                       const float* w_hh, const float* b_hh,
                       const float* w1,const float* b1,const float* w2,const float* b2,
                       const float* w3,const float* b3,
                       float* consts){
  __shared__ float hl[128];
  __shared__ float z1[32];
  __shared__ float z2[32];
  int t = threadIdx.x;
  float h = emd_w[t] + emd_b[t];
  hl[t] = h; consts[t] = h;
  __syncthreads();
  float s = agg_b[t];
  for(int k=0;k<128;k++) s += agg_w[t*128+k]*hl[k];
  consts[128+t] = s;
  for(int g=t; g<G3; g+=128){
    float q = b_hh[g];
    for(int k=0;k<128;k++) q += w_hh[g*128+k]*hl[k];
    consts[256+g] = q;
  }
  if(t<32){
    float a = b1[t];
    for(int k=0;k<128;k++) a += w1[t*128+k]*hl[k];
    z1[t] = fmaxf(a,0.f);
  }
  __syncthreads();
  if(t<32){
    float a = b2[t];
    for(int k=0;k<32;k++) a += w2[t*32+k]*z1[k];
    z2[t] = fmaxf(a,0.f);
  }
  __syncthreads();
  if(t==0){
    float a = b3[0];
    for(int k=0;k<32;k++) a += w3[k]*z2[k];
    consts[640] = a;
  }
}

// ---------------- histogram nodes + edges by level ----------------
// ints layout: node_cnt@0(16) node_off@32(17) node_fill@64(16) edge_cnt@96(16) edge_off@128(17) edge_fill@160(16)
__global__ void k_count(const int* ei, const int* fl, int N, int E, int* ints){
  int i = blockIdx.x*blockDim.x+threadIdx.x;
  int stride = gridDim.x*blockDim.x;
  for(int j=i;j<N;j+=stride) atomicAdd(&ints[0 + fl[j]], 1);
  for(int j=i;j<E;j+=stride) atomicAdd(&ints[96 + fl[ei[E+j]]], 1);
}

__global__ void k_prefix(int* ints){
  if(threadIdx.x==0 && blockIdx.x==0){
    int o=0;
    for(int l=0;l<NLEV;l++){ ints[32+l]=o; ints[64+l]=o; o+=ints[l]; }
    ints[32+NLEV]=o;
    o=0;
    for(int l=0;l<NLEV;l++){ ints[128+l]=o; ints[160+l]=o; o+=ints[96+l]; }
    ints[128+NLEV]=o;
  }
}

__global__ void k_build(const int* ei, const int* fl, int N, int E, int* ints,
                        int* node_list, int* node_rank, int* edge_list){
  int i = blockIdx.x*blockDim.x+threadIdx.x;
  int stride = gridDim.x*blockDim.x;
  for(int j=i;j<N;j+=stride){
    int lev = fl[j];
    int pos = atomicAdd(&ints[64+lev],1);
    node_list[pos]=j;
    node_rank[j]=pos-ints[32+lev];
  }
  for(int j=i;j<E;j+=stride){
    int lev = fl[ei[E+j]];
    int pos = atomicAdd(&ints[160+lev],1);
    edge_list[pos]=j;
  }
}

// ---------------- broadcast t_init, init out=c0 ----------------
__global__ void k_bcast(float* tbuf, float* out, const float* consts, int N){
  long long i = (long long)blockIdx.x*blockDim.x+threadIdx.x;
  long long stride = (long long)gridDim.x*blockDim.x;
  float4* t4 = (float4*)tbuf;
  const float4* ti4 = (const float4*)(consts+128);
  long long n4 = (long long)N*32;
  for(long long j=i;j<n4;j+=stride) t4[j] = ti4[j & 31];
  float c0 = consts[640];
  for(long long j=i;j<N;j+=stride) out[j]=c0;
}

// ---------------- scatter t[src] into compact msg rows for level l ----------------
__global__ void k_scatter(const int* ei, const int* edge_list, const int* node_rank,
                          const float* tbuf, float* msgC, const int* ints, int E, int l){
  int base = ints[128+l];
  int cnt  = ints[96+l];
  long long items = (long long)cnt*32;
  long long i = (long long)blockIdx.x*blockDim.x+threadIdx.x;
  long long stride = (long long)gridDim.x*blockDim.x;
  const float4* t4 = (const float4*)tbuf;
  for(long long w=i;w<items;w+=stride){
    int e_i = (int)(w>>5);
    int c   = (int)(w&31);
    int e  = edge_list[base+e_i];
    int s  = ei[e];
    int tg = ei[E+e];
    int r  = node_rank[tg];
    float4 v = t4[(long long)s*32+c];
    float* m = msgC + (long long)r*128 + c*4;
    atomicAdd(m+0,v.x); atomicAdd(m+1,v.y); atomicAdd(m+2,v.z); atomicAdd(m+3,v.w);
  }
}

// ---------------- fused per-level: GEMM(gi) + GRU gates + GEMM(t) + MLP ----------------
// smem floats: inp@0 [32][148]=4736 | wl@4736 (6208) | hl@10944 [32][129]=4128 | z1l@15072 (1152)
// z2l aliases inp region (dead by then). total 16224 floats = 64896 B (< 64 KiB)
__global__ __launch_bounds__(256) void k_fused(
    const float* x, const int* node_list, float* msgC, float* tbuf,
    const float* w_ih, const float* b_ih, const float* agg_w, const float* agg_b,
    const float* w1,const float* b1,const float* w2,const float* b2,
    const float* w3,const float* b3,
    const float* consts, float* out, const int* ints, int l)
{
  __shared__ __align__(16) float smem[16224];
  float (*inp)[148] = (float(*)[148])smem;
  float *wl  = smem + 4736;
  float (*hl)[129] = (float(*)[129])(smem + 10944);
  float *z1l = smem + 15072;
  float *z2l = smem;             // alias inp (dead after GEMM1)

  int base = ints[32+l];
  int cnt  = ints[0+l];
  int tiles = (cnt+31)>>5;
  int tid = threadIdx.x;
  int tx = tid & 31;   // dim group: dims tx*4..tx*4+3
  int ty = tid >> 5;   // node group: nodes ty*4..ty*4+3

  for(int tile = blockIdx.x; tile < tiles; tile += gridDim.x){
    int n0 = tile*32;
    // ---- stage inputs: msg rows (read+clear) and x ----
    for(int idx=tid; idx<32*128; idx+=256){
      int i = idx>>7, k = idx&127;
      long long mrow = (long long)(n0+i)*128 + k;
      float v = msgC[mrow];
      msgC[mrow] = 0.f;          // consume-and-clear so next level's scatter sees zeros
      inp[i][k] = v;
    }
    for(int idx=tid; idx<32*16; idx+=256){
      int i = idx>>4, j = idx&15;
      int gi = n0+i;
      int vq = node_list[base + ((gi<cnt)?gi:0)];
      inp[i][128+j] = (gi<cnt)? x[(long long)vq*16+j] : 0.f;
    }
    __syncthreads();

    // ---- GEMM1: gi = W_ih @ [msg,x] + b_ih, 3 gates per output dim ----
    float ar[4][4], az[4][4], an[4][4];
    #pragma unroll
    for(int di=0;di<4;di++){
      float br = b_ih[tx*4+di], bz = b_ih[128+tx*4+di], bn = b_ih[256+tx*4+di];
      #pragma unroll
      for(int ni=0;ni<4;ni++){ ar[ni][di]=br; az[ni][di]=bz; an[ni][di]=bn; }
    }
    for(int k0=0;k0<DIN;k0+=16){
      for(int idx=tid; idx<G3*16; idx+=256){
        int kk = idx&15, g = idx>>4;
        wl[kk*388+g] = w_ih[g*DIN + k0 + kk];
      }
      __syncthreads();
      #pragma unroll 4
      for(int kk=0;kk<16;kk++){
        float4 wr = *(const float4*)&wl[kk*388 + tx*4];
        float4 wz = *(const float4*)&wl[kk*388 + 128 + tx*4];
        float4 wn = *(const float4*)&wl[kk*388 + 256 + tx*4];
        int k = k0+kk;
        float av[4] = { inp[ty*4+0][k], inp[ty*4+1][k], inp[ty*4+2][k], inp[ty*4+3][k] };
        float wrv[4]={wr.x,wr.y,wr.z,wr.w};
        float wzv[4]={wz.x,wz.y,wz.z,wz.w};
        float wnv[4]={wn.x,wn.y,wn.z,wn.w};
        #pragma unroll
        for(int ni=0;ni<4;ni++){
          #pragma unroll
          for(int di=0;di<4;di++){
            ar[ni][di] += av[ni]*wrv[di];
            az[ni][di] += av[ni]*wzv[di];
            an[ni][di] += av[ni]*wnv[di];
          }
        }
      }
      __syncthreads();
    }

    // ---- GRU gates -> h_new into LDS ----
    #pragma unroll
    for(int ni=0;ni<4;ni++){
      int i = ty*4+ni;
      #pragma unroll
      for(int di=0;di<4;di++){
        int d = tx*4+di;
        float r = sigmoidf_(ar[ni][di] + consts[256+d]);
        float z = sigmoidf_(az[ni][di] + consts[384+d]);
        float n = tanhf(an[ni][di] + r*consts[512+d]);
        hl[i][d] = (1.f-z)*n + z*consts[d];
      }
    }
    __syncthreads();

    // ---- GEMM2: t = agg_w @ h_new + agg_b ----
    float ac[4][4];
    #pragma unroll
    for(int di=0;di<4;di++){
      float b = agg_b[tx*4+di];
      #pragma unroll
      for(int ni=0;ni<4;ni++) ac[ni][di]=b;
    }
    for(int k0=0;k0<DHID;k0+=16){
      for(int idx=tid; idx<DHID*16; idx+=256){
        int kk = idx&15, g = idx>>4;
        wl[kk*132+g] = agg_w[g*DHID + k0 + kk];
      }
      __syncthreads();
      #pragma unroll 4
      for(int kk=0;kk<16;kk++){
        float4 wv = *(const float4*)&wl[kk*132 + tx*4];
        int k = k0+kk;
        float av[4] = { hl[ty*4+0][k], hl[ty*4+1][k], hl[ty*4+2][k], hl[ty*4+3][k] };
        float wvv[4]={wv.x,wv.y,wv.z,wv.w};
        #pragma unroll
        for(int ni=0;ni<4;ni++){
          #pragma unroll
          for(int di=0;di<4;di++) ac[ni][di] += av[ni]*wvv[di];
        }
      }
      __syncthreads();
    }
    #pragma unroll
    for(int ni=0;ni<4;ni++){
      int i = ty*4+ni; int gi = n0+i;
      if(gi<cnt){
        int v = node_list[base+gi];
        ((float4*)tbuf)[(long long)v*32+tx] = make_float4(ac[ni][0],ac[ni][1],ac[ni][2],ac[ni][3]);
      }
    }

    // ---- MLP from hl -> out ----
    for(int idx=tid; idx<4096; idx+=256){
      int j = idx>>7, k = idx&127;
      wl[k*36+j] = w1[idx];
    }
    __syncthreads();
    {
      int i = tid>>3;
      int jb = (tid&7)*4;
      float s[4];
      #pragma unroll
      for(int jj=0;jj<4;jj++) s[jj]=b1[jb+jj];
      for(int k=0;k<128;k++){
        float hv = hl[i][k];
        #pragma unroll
        for(int jj=0;jj<4;jj++) s[jj] += hv*wl[k*36+jb+jj];
      }
      #pragma unroll
      for(int jj=0;jj<4;jj++) z1l[i*36+jb+jj] = fmaxf(s[jj],0.f);
    }
    __syncthreads();
    for(int idx=tid; idx<1024; idx+=256){
      int j = idx>>5, k = idx&31;
      wl[k*36+j] = w2[idx];
    }
    __syncthreads();
    {
      int i = tid>>3;
      int jb = (tid&7)*4;
      float s[4];
      #pragma unroll
      for(int jj=0;jj<4;jj++) s[jj]=b2[jb+jj];
      for(int k=0;k<32;k++){
        float zv = z1l[i*36+k];
        #pragma unroll
        for(int jj=0;jj<4;jj++) s[jj] += zv*wl[k*36+jb+jj];
      }
      #pragma unroll
      for(int jj=0;jj<4;jj++) z2l[i*36+jb+jj] = fmaxf(s[jj],0.f);
    }
    __syncthreads();
    if(tid<32){
      int gi = n0+tid;
      if(gi<cnt){
        float s = b3[0];
        for(int k=0;k<32;k++) s += z2l[tid*36+k]*w3[k];
        out[node_list[base+gi]] = s;
      }
    }
    __syncthreads();   // protect LDS before next tile
  }
}

extern "C" void kernel_launch(void* const* d_in, const int* in_sizes, int n_in,
                              void* d_out, int out_size, void* d_ws, size_t ws_size,
                              hipStream_t stream){
  const float* x     = (const float*)d_in[0];
  const int*   ei    = (const int*)  d_in[1];
  const int*   fl    = (const int*)  d_in[2];
  const float* emd_w = (const float*)d_in[4];
  const float* emd_b = (const float*)d_in[5];
  const float* agg_w = (const float*)d_in[6];
  const float* agg_b = (const float*)d_in[7];
  const float* w_ih  = (const float*)d_in[8];
  const float* w_hh  = (const float*)d_in[9];
  const float* b_ih  = (const float*)d_in[10];
  const float* b_hh  = (const float*)d_in[11];
  const float* w1    = (const float*)d_in[12];
  const float* b1    = (const float*)d_in[13];
  const float* w2    = (const float*)d_in[14];
  const float* b2    = (const float*)d_in[15];
  const float* w3    = (const float*)d_in[16];
  const float* b3    = (const float*)d_in[17];
  float* out = (float*)d_out;

  int N = in_sizes[2];
  int E = in_sizes[1]/2;

  char* ws = (char*)d_ws;
  float* consts   = (float*)ws;                    // 4 KiB
  int*   ints     = (int*)(ws + 4096);             // 4 KiB
  int*   node_list= (int*)(ws + 8192);
  int*   node_rank= node_list + N;
  int*   edge_list= node_rank + N;
  size_t off = 8192 + (size_t)(2*N+E)*4;
  off = (off + 255) & ~(size_t)255;
  float* msgC = (float*)(ws + off);                // (N+32)*128 floats
  size_t msg_bytes = (size_t)(N+32)*128*4;
  float* tbuf = (float*)(ws + off + msg_bytes);    // N*128 floats
  size_t need = off + msg_bytes + (size_t)N*128*4;
  if(ws_size < need) return;  // workspace too small; fail loudly via validation

  long long n4 = (long long)(N+32)*32;
  k_zero   <<<4096,256,0,stream>>>(msgC, n4, ints, 256);
  k_init   <<<1,128,0,stream>>>(emd_w,emd_b,agg_w,agg_b,w_hh,b_hh,w1,b1,w2,b2,w3,b3,consts);
  k_count  <<<1600,256,0,stream>>>(ei,fl,N,E,ints);
  k_prefix <<<1,1,0,stream>>>(ints);
  k_build  <<<1600,256,0,stream>>>(ei,fl,N,E,ints,node_list,node_rank,edge_list);
  k_bcast  <<<2048,256,0,stream>>>(tbuf,out,consts,N);
  for(int l=1;l<NLEV;l++){
    k_scatter<<<1024,256,0,stream>>>(ei,edge_list,node_rank,tbuf,msgC,ints,E,l);
    k_fused  <<<512,256,0,stream>>>(x,node_list,msgC,tbuf,w_ih,b_ih,agg_w,agg_b,
                                    w1,b1,w2,b2,w3,b3,consts,out,ints,l);
  }
}

// Round 2
// 1903.873 us; speedup vs baseline: 2.5304x; 2.5304x over previous
//
#include <hip/hip_runtime.h>
#include <math.h>

// Problem dims (fixed by the reference file)
#define DHID 128
#define DXIN 16
#define DIN  144   // DHID + DXIN
#define G3   384   // 3*DHID
#define NLEV 16

__device__ __forceinline__ float sigmoidf_(float v){ return 1.0f/(1.0f + __expf(-v)); }

// ---------------- zero workspace (msg buffer + counters) ----------------
__global__ void k_zero(float* msgC, long long n4, int* ints, int nints){
  long long i = (long long)blockIdx.x*blockDim.x + threadIdx.x;
  long long stride = (long long)gridDim.x*blockDim.x;
  float4 z = make_float4(0.f,0.f,0.f,0.f);
  float4* m4 = (float4*)msgC;
  for(long long j=i;j<n4;j+=stride) m4[j]=z;
  if(i<nints) ints[i]=0;
}

// ---------------- precompute h_init, t_init, gh_init, c0 ----------------
// consts layout (floats): [0..127]=h_init [128..255]=t_init [256..639]=gh_init [640]=c0
__global__ void k_init(const float* emd_w, const float* emd_b,
                       const float* agg_w, const float* agg_b,
                       const float* w_hh, const float* b_hh,
                       const float* w1,const float* b1,const float* w2,const float* b2,
                       const float* w3,const float* b3,
                       float* consts){
  __shared__ float hl[128];
  __shared__ float z1[32];
  __shared__ float z2[32];
  int t = threadIdx.x;
  float h = emd_w[t] + emd_b[t];
  hl[t] = h; consts[t] = h;
  __syncthreads();
  float s = agg_b[t];
  for(int k=0;k<128;k++) s += agg_w[t*128+k]*hl[k];
  consts[128+t] = s;
  for(int g=t; g<G3; g+=128){
    float q = b_hh[g];
    for(int k=0;k<128;k++) q += w_hh[g*128+k]*hl[k];
    consts[256+g] = q;
  }
  if(t<32){
    float a = b1[t];
    for(int k=0;k<128;k++) a += w1[t*128+k]*hl[k];
    z1[t] = fmaxf(a,0.f);
  }
  __syncthreads();
  if(t<32){
    float a = b2[t];
    for(int k=0;k<32;k++) a += w2[t*32+k]*z1[k];
    z2[t] = fmaxf(a,0.f);
  }
  __syncthreads();
  if(t==0){
    float a = b3[0];
    for(int k=0;k<32;k++) a += w3[k]*z2[k];
    consts[640] = a;
  }
}

// ---------------- histogram nodes + edges by level (LDS hist, low contention) ---
// ints layout: node_cnt@0(16) node_off@32(17) node_fill@64(16) edge_cnt@96(16) edge_off@128(17) edge_fill@160(16)
__global__ void k_count(const int* ei, const int* fl, int N, int E, int* ints){
  __shared__ int hn[16], he[16];
  int tid = threadIdx.x;
  if(tid<16){ hn[tid]=0; he[tid]=0; }
  __syncthreads();
  int i = blockIdx.x*blockDim.x+tid;
  int stride = gridDim.x*blockDim.x;
  for(int j=i;j<N;j+=stride) atomicAdd(&hn[fl[j]], 1);
  for(int j=i;j<E;j+=stride) atomicAdd(&he[fl[ei[E+j]]], 1);
  __syncthreads();
  if(tid<16){
    if(hn[tid]) atomicAdd(&ints[0 + tid], hn[tid]);
    if(he[tid]) atomicAdd(&ints[96 + tid], he[tid]);
  }
}

__global__ void k_prefix(int* ints){
  if(threadIdx.x==0 && blockIdx.x==0){
    int o=0;
    for(int l=0;l<NLEV;l++){ ints[32+l]=o; ints[64+l]=o; o+=ints[l]; }
    ints[32+NLEV]=o;
    o=0;
    for(int l=0;l<NLEV;l++){ ints[128+l]=o; ints[160+l]=o; o+=ints[96+l]; }
    ints[128+NLEV]=o;
  }
}

// Two-pass per-block counting sort: LDS hist -> reserve block base (1 global
// atomic per bin per block) -> place items at base + local LDS rank.
__global__ void k_build(const int* ei, const int* fl, int N, int E, int* ints,
                        int* node_list, int* node_rank, int* edge_list){
  __shared__ int h[16], base[16];
  int tid = threadIdx.x;

  // ---- nodes: contiguous chunk per block ----
  int nchunk = (N + gridDim.x - 1)/gridDim.x;
  int lo = blockIdx.x*nchunk;
  int hi = lo + nchunk; if(hi>N) hi=N;
  if(tid<16) h[tid]=0;
  __syncthreads();
  for(int j=lo+tid; j<hi; j+=blockDim.x) atomicAdd(&h[fl[j]],1);
  __syncthreads();
  if(tid<16){ base[tid] = h[tid] ? atomicAdd(&ints[64+tid], h[tid]) : 0; h[tid]=0; }
  __syncthreads();
  for(int j=lo+tid; j<hi; j+=blockDim.x){
    int lev = fl[j];
    int pos = base[lev] + atomicAdd(&h[lev],1);
    node_list[pos]=j;
    node_rank[j]=pos-ints[32+lev];
  }
  __syncthreads();

  // ---- edges ----
  int echunk = (E + gridDim.x - 1)/gridDim.x;
  lo = blockIdx.x*echunk;
  hi = lo + echunk; if(hi>E) hi=E;
  if(tid<16) h[tid]=0;
  __syncthreads();
  for(int j=lo+tid; j<hi; j+=blockDim.x) atomicAdd(&h[fl[ei[E+j]]],1);
  __syncthreads();
  if(tid<16){ base[tid] = h[tid] ? atomicAdd(&ints[160+tid], h[tid]) : 0; h[tid]=0; }
  __syncthreads();
  for(int j=lo+tid; j<hi; j+=blockDim.x){
    int lev = fl[ei[E+j]];
    int pos = base[lev] + atomicAdd(&h[lev],1);
    edge_list[pos]=j;
  }
}

// ---------------- broadcast t_init, init out=c0 ----------------
__global__ void k_bcast(float* tbuf, float* out, const float* consts, int N){
  long long i = (long long)blockIdx.x*blockDim.x+threadIdx.x;
  long long stride = (long long)gridDim.x*blockDim.x;
  float4* t4 = (float4*)tbuf;
  const float4* ti4 = (const float4*)(consts+128);
  long long n4 = (long long)N*32;
  for(long long j=i;j<n4;j+=stride) t4[j] = ti4[j & 31];
  float c0 = consts[640];
  for(long long j=i;j<N;j+=stride) out[j]=c0;
}

// ---------------- scatter t[src] into compact msg rows for level l ----------------
__global__ void k_scatter(const int* ei, const int* edge_list, const int* node_rank,
                          const float* tbuf, float* msgC, const int* ints, int E, int l){
  int base = ints[128+l];
  int cnt  = ints[96+l];
  long long items = (long long)cnt*32;
  long long i = (long long)blockIdx.x*blockDim.x+threadIdx.x;
  long long stride = (long long)gridDim.x*blockDim.x;
  const float4* t4 = (const float4*)tbuf;
  for(long long w=i;w<items;w+=stride){
    int e_i = (int)(w>>5);
    int c   = (int)(w&31);
    int e  = edge_list[base+e_i];
    int s  = ei[e];
    int tg = ei[E+e];
    int r  = node_rank[tg];
    float4 v = t4[(long long)s*32+c];
    float* m = msgC + (long long)r*128 + c*4;
    atomicAdd(m+0,v.x); atomicAdd(m+1,v.y); atomicAdd(m+2,v.z); atomicAdd(m+3,v.w);
  }
}

// ---------------- fused per-level: GEMM(gi) + GRU gates + GEMM(t) + MLP ----------------
// smem floats: inp@0 [32][148]=4736 | wl@4736 (6208) | hl@10944 [32][129]=4128 | z1l@15072 (1152)
// z2l aliases inp region (dead by then). total 16224 floats = 64896 B (< 64 KiB)
__global__ __launch_bounds__(256) void k_fused(
    const float* x, const int* node_list, float* msgC, float* tbuf,
    const float* w_ih, const float* b_ih, const float* agg_w, const float* agg_b,
    const float* w1,const float* b1,const float* w2,const float* b2,
    const float* w3,const float* b3,
    const float* consts, float* out, const int* ints, int l)
{
  __shared__ __align__(16) float smem[16224];
  float (*inp)[148] = (float(*)[148])smem;
  float *wl  = smem + 4736;
  float (*hl)[129] = (float(*)[129])(smem + 10944);
  float *z1l = smem + 15072;
  float *z2l = smem;             // alias inp (dead after GEMM1)

  int base = ints[32+l];
  int cnt  = ints[0+l];
  int tiles = (cnt+31)>>5;
  int tid = threadIdx.x;
  int tx = tid & 31;   // dim group: dims tx*4..tx*4+3
  int ty = tid >> 5;   // node group: nodes ty*4..ty*4+3

  for(int tile = blockIdx.x; tile < tiles; tile += gridDim.x){
    int n0 = tile*32;
    // ---- stage inputs: msg rows (read+clear) and x ----
    for(int idx=tid; idx<32*128; idx+=256){
      int i = idx>>7, k = idx&127;
      long long mrow = (long long)(n0+i)*128 + k;
      float v = msgC[mrow];
      msgC[mrow] = 0.f;          // consume-and-clear so next level's scatter sees zeros
      inp[i][k] = v;
    }
    for(int idx=tid; idx<32*16; idx+=256){
      int i = idx>>4, j = idx&15;
      int gi = n0+i;
      int vq = node_list[base + ((gi<cnt)?gi:0)];
      inp[i][128+j] = (gi<cnt)? x[(long long)vq*16+j] : 0.f;
    }
    __syncthreads();

    // ---- GEMM1: gi = W_ih @ [msg,x] + b_ih, 3 gates per output dim ----
    float ar[4][4], az[4][4], an[4][4];
    #pragma unroll
    for(int di=0;di<4;di++){
      float br = b_ih[tx*4+di], bz = b_ih[128+tx*4+di], bn = b_ih[256+tx*4+di];
      #pragma unroll
      for(int ni=0;ni<4;ni++){ ar[ni][di]=br; az[ni][di]=bz; an[ni][di]=bn; }
    }
    for(int k0=0;k0<DIN;k0+=16){
      for(int idx=tid; idx<G3*16; idx+=256){
        int kk = idx&15, g = idx>>4;
        wl[kk*388+g] = w_ih[g*DIN + k0 + kk];
      }
      __syncthreads();
      #pragma unroll 4
      for(int kk=0;kk<16;kk++){
        float4 wr = *(const float4*)&wl[kk*388 + tx*4];
        float4 wz = *(const float4*)&wl[kk*388 + 128 + tx*4];
        float4 wn = *(const float4*)&wl[kk*388 + 256 + tx*4];
        int k = k0+kk;
        float av[4] = { inp[ty*4+0][k], inp[ty*4+1][k], inp[ty*4+2][k], inp[ty*4+3][k] };
        float wrv[4]={wr.x,wr.y,wr.z,wr.w};
        float wzv[4]={wz.x,wz.y,wz.z,wz.w};
        float wnv[4]={wn.x,wn.y,wn.z,wn.w};
        #pragma unroll
        for(int ni=0;ni<4;ni++){
          #pragma unroll
          for(int di=0;di<4;di++){
            ar[ni][di] += av[ni]*wrv[di];
            az[ni][di] += av[ni]*wzv[di];
            an[ni][di] += av[ni]*wnv[di];
          }
        }
      }
      __syncthreads();
    }

    // ---- GRU gates -> h_new into LDS ----
    #pragma unroll
    for(int ni=0;ni<4;ni++){
      int i = ty*4+ni;
      #pragma unroll
      for(int di=0;di<4;di++){
        int d = tx*4+di;
        float r = sigmoidf_(ar[ni][di] + consts[256+d]);
        float z = sigmoidf_(az[ni][di] + consts[384+d]);
        float n = tanhf(an[ni][di] + r*consts[512+d]);
        hl[i][d] = (1.f-z)*n + z*consts[d];
      }
    }
    __syncthreads();

    // ---- GEMM2: t = agg_w @ h_new + agg_b ----
    float ac[4][4];
    #pragma unroll
    for(int di=0;di<4;di++){
      float b = agg_b[tx*4+di];
      #pragma unroll
      for(int ni=0;ni<4;ni++) ac[ni][di]=b;
    }
    for(int k0=0;k0<DHID;k0+=16){
      for(int idx=tid; idx<DHID*16; idx+=256){
        int kk = idx&15, g = idx>>4;
        wl[kk*132+g] = agg_w[g*DHID + k0 + kk];
      }
      __syncthreads();
      #pragma unroll 4
      for(int kk=0;kk<16;kk++){
        float4 wv = *(const float4*)&wl[kk*132 + tx*4];
        int k = k0+kk;
        float av[4] = { hl[ty*4+0][k], hl[ty*4+1][k], hl[ty*4+2][k], hl[ty*4+3][k] };
        float wvv[4]={wv.x,wv.y,wv.z,wv.w};
        #pragma unroll
        for(int ni=0;ni<4;ni++){
          #pragma unroll
          for(int di=0;di<4;di++) ac[ni][di] += av[ni]*wvv[di];
        }
      }
      __syncthreads();
    }
    #pragma unroll
    for(int ni=0;ni<4;ni++){
      int i = ty*4+ni; int gi = n0+i;
      if(gi<cnt){
        int v = node_list[base+gi];
        ((float4*)tbuf)[(long long)v*32+tx] = make_float4(ac[ni][0],ac[ni][1],ac[ni][2],ac[ni][3]);
      }
    }

    // ---- MLP from hl -> out ----
    for(int idx=tid; idx<4096; idx+=256){
      int j = idx>>7, k = idx&127;
      wl[k*36+j] = w1[idx];
    }
    __syncthreads();
    {
      int i = tid>>3;
      int jb = (tid&7)*4;
      float s[4];
      #pragma unroll
      for(int jj=0;jj<4;jj++) s[jj]=b1[jb+jj];
      for(int k=0;k<128;k++){
        float hv = hl[i][k];
        #pragma unroll
        for(int jj=0;jj<4;jj++) s[jj] += hv*wl[k*36+jb+jj];
      }
      #pragma unroll
      for(int jj=0;jj<4;jj++) z1l[i*36+jb+jj] = fmaxf(s[jj],0.f);
    }
    __syncthreads();
    for(int idx=tid; idx<1024; idx+=256){
      int j = idx>>5, k = idx&31;
      wl[k*36+j] = w2[idx];
    }
    __syncthreads();
    {
      int i = tid>>3;
      int jb = (tid&7)*4;
      float s[4];
      #pragma unroll
      for(int jj=0;jj<4;jj++) s[jj]=b2[jb+jj];
      for(int k=0;k<32;k++){
        float zv = z1l[i*36+k];
        #pragma unroll
        for(int jj=0;jj<4;jj++) s[jj] += zv*wl[k*36+jb+jj];
      }
      #pragma unroll
      for(int jj=0;jj<4;jj++) z2l[i*36+jb+jj] = fmaxf(s[jj],0.f);
    }
    __syncthreads();
    if(tid<32){
      int gi = n0+tid;
      if(gi<cnt){
        float s = b3[0];
        for(int k=0;k<32;k++) s += z2l[tid*36+k]*w3[k];
        out[node_list[base+gi]] = s;
      }
    }
    __syncthreads();   // protect LDS before next tile
  }
}

extern "C" void kernel_launch(void* const* d_in, const int* in_sizes, int n_in,
                              void* d_out, int out_size, void* d_ws, size_t ws_size,
                              hipStream_t stream){
  const float* x     = (const float*)d_in[0];
  const int*   ei    = (const int*)  d_in[1];
  const int*   fl    = (const int*)  d_in[2];
  const float* emd_w = (const float*)d_in[4];
  const float* emd_b = (const float*)d_in[5];
  const float* agg_w = (const float*)d_in[6];
  const float* agg_b = (const float*)d_in[7];
  const float* w_ih  = (const float*)d_in[8];
  const float* w_hh  = (const float*)d_in[9];
  const float* b_ih  = (const float*)d_in[10];
  const float* b_hh  = (const float*)d_in[11];
  const float* w1    = (const float*)d_in[12];
  const float* b1    = (const float*)d_in[13];
  const float* w2    = (const float*)d_in[14];
  const float* b2    = (const float*)d_in[15];
  const float* w3    = (const float*)d_in[16];
  const float* b3    = (const float*)d_in[17];
  float* out = (float*)d_out;

  int N = in_sizes[2];
  int E = in_sizes[1]/2;

  char* ws = (char*)d_ws;
  float* consts   = (float*)ws;                    // 4 KiB
  int*   ints     = (int*)(ws + 4096);             // 4 KiB
  int*   node_list= (int*)(ws + 8192);
  int*   node_rank= node_list + N;
  int*   edge_list= node_rank + N;
  size_t off = 8192 + (size_t)(2*N+E)*4;
  off = (off + 255) & ~(size_t)255;
  float* msgC = (float*)(ws + off);                // (N+32)*128 floats
  size_t msg_bytes = (size_t)(N+32)*128*4;
  float* tbuf = (float*)(ws + off + msg_bytes);    // N*128 floats
  size_t need = off + msg_bytes + (size_t)N*128*4;
  if(ws_size < need) return;  // workspace too small; fail loudly via validation

  long long n4 = (long long)(N+32)*32;
  k_zero   <<<4096,256,0,stream>>>(msgC, n4, ints, 256);
  k_init   <<<1,128,0,stream>>>(emd_w,emd_b,agg_w,agg_b,w_hh,b_hh,w1,b1,w2,b2,w3,b3,consts);
  k_count  <<<512,256,0,stream>>>(ei,fl,N,E,ints);
  k_prefix <<<1,1,0,stream>>>(ints);
  k_build  <<<512,256,0,stream>>>(ei,fl,N,E,ints,node_list,node_rank,edge_list);
  k_bcast  <<<2048,256,0,stream>>>(tbuf,out,consts,N);
  for(int l=1;l<NLEV;l++){
    k_scatter<<<1024,256,0,stream>>>(ei,edge_list,node_rank,tbuf,msgC,ints,E,l);
    k_fused  <<<512,256,0,stream>>>(x,node_list,msgC,tbuf,w_ih,b_ih,agg_w,agg_b,
                                    w1,b1,w2,b2,w3,b3,consts,out,ints,l);
  }
}

// Round 3
// 1553.082 us; speedup vs baseline: 3.1020x; 1.2259x over previous
//
#include <hip/hip_runtime.h>
#include <math.h>

// Problem dims (fixed by the reference file)
#define DHID 128
#define DXIN 16
#define DIN  144   // DHID + DXIN
#define G3   384   // 3*DHID
#define NLEV 16
#define SCAN_CHUNK 2048

__device__ __forceinline__ float sigmoidf_(float v){ return 1.0f/(1.0f + __expf(-v)); }
__device__ __forceinline__ float tanhf_(float v){
  v = fminf(fmaxf(v,-15.f),15.f);
  float e = __expf(2.f*v);
  return (e-1.f)/(e+1.f);
}

// ---------------- zero counters / indeg / fill ----------------
__global__ void k_zero0(int* ints, int* indeg, int* fill, int N){
  int i = blockIdx.x*blockDim.x + threadIdx.x;
  int stride = gridDim.x*blockDim.x;
  if(i<256) ints[i]=0;
  for(int j=i;j<N;j+=stride){ indeg[j]=0; fill[j]=0; }
}

// ---------------- precompute h_init, t_init, gh_init, c0 ----------------
// consts layout (floats): [0..127]=h_init [128..255]=t_init [256..639]=gh_init [640]=c0
__global__ void k_init(const float* emd_w, const float* emd_b,
                       const float* agg_w, const float* agg_b,
                       const float* w_hh, const float* b_hh,
                       const float* w1,const float* b1,const float* w2,const float* b2,
                       const float* w3,const float* b3,
                       float* consts){
  __shared__ float hl[128];
  __shared__ float z1[32];
  __shared__ float z2[32];
  int t = threadIdx.x;
  float h = emd_w[t] + emd_b[t];
  hl[t] = h; consts[t] = h;
  __syncthreads();
  float s = agg_b[t];
  for(int k=0;k<128;k++) s += agg_w[t*128+k]*hl[k];
  consts[128+t] = s;
  for(int g=t; g<G3; g+=128){
    float q = b_hh[g];
    for(int k=0;k<128;k++) q += w_hh[g*128+k]*hl[k];
    consts[256+g] = q;
  }
  if(t<32){
    float a = b1[t];
    for(int k=0;k<128;k++) a += w1[t*128+k]*hl[k];
    z1[t] = fmaxf(a,0.f);
  }
  __syncthreads();
  if(t<32){
    float a = b2[t];
    for(int k=0;k<32;k++) a += w2[t*32+k]*z1[k];
    z2[t] = fmaxf(a,0.f);
  }
  __syncthreads();
  if(t==0){
    float a = b3[0];
    for(int k=0;k<32;k++) a += w3[k]*z2[k];
    consts[640] = a;
  }
}

// ---------------- node histogram by level (LDS hist) ----------------
// ints layout: node_cnt@0(16) node_off@32(17) node_fill@64(16)
__global__ void k_count(const int* fl, int N, int* ints){
  __shared__ int hn[16];
  int tid = threadIdx.x;
  if(tid<16) hn[tid]=0;
  __syncthreads();
  int i = blockIdx.x*blockDim.x+tid;
  int stride = gridDim.x*blockDim.x;
  for(int j=i;j<N;j+=stride) atomicAdd(&hn[fl[j]], 1);
  __syncthreads();
  if(tid<16 && hn[tid]) atomicAdd(&ints[tid], hn[tid]);
}

__global__ void k_prefix(int* ints){
  if(threadIdx.x==0 && blockIdx.x==0){
    int o=0;
    for(int l=0;l<NLEV;l++){ ints[32+l]=o; ints[64+l]=o; o+=ints[l]; }
    ints[32+NLEV]=o;
  }
}

// Two-pass per-block counting sort of nodes by level.
__global__ void k_build(const int* fl, int N, int* ints,
                        int* node_list, int* node_rank){
  __shared__ int h[16], base[16];
  int tid = threadIdx.x;
  int nchunk = (N + gridDim.x - 1)/gridDim.x;
  int lo = blockIdx.x*nchunk;
  int hi = lo + nchunk; if(hi>N) hi=N;
  if(tid<16) h[tid]=0;
  __syncthreads();
  for(int j=lo+tid; j<hi; j+=blockDim.x) atomicAdd(&h[fl[j]],1);
  __syncthreads();
  if(tid<16){ base[tid] = h[tid] ? atomicAdd(&ints[64+tid], h[tid]) : 0; h[tid]=0; }
  __syncthreads();
  for(int j=lo+tid; j<hi; j+=blockDim.x){
    int lev = fl[j];
    int pos = base[lev] + atomicAdd(&h[lev],1);
    node_list[pos]=j;
    node_rank[j]=pos-ints[32+lev];
  }
}

// ---------------- indegree histogram over permuted node positions ----------------
__global__ void k_indeg(const int* ei, const int* fl, const int* node_rank,
                        const int* ints, int* indeg, int E){
  int i = blockIdx.x*blockDim.x+threadIdx.x;
  int stride = gridDim.x*blockDim.x;
  for(int e=i;e<E;e+=stride){
    int tg = ei[E+e];
    int p = ints[32+fl[tg]] + node_rank[tg];
    atomicAdd(&indeg[p],1);
  }
}

// ---------------- hierarchical exclusive scan of indeg -> row_ptr ----------------
__global__ void k_scan_a(const int* indeg, int* bsum, int N){
  __shared__ int ts[256];
  int b=blockIdx.x, t=threadIdx.x;
  int base=b*SCAN_CHUNK+t*8; int s=0;
  for(int j=0;j<8;j++){ int idx=base+j; if(idx<N) s+=indeg[idx]; }
  ts[t]=s; __syncthreads();
  for(int off=128;off>0;off>>=1){ if(t<off) ts[t]+=ts[t+off]; __syncthreads(); }
  if(t==0) bsum[b]=ts[0];
}
__global__ void k_scan_b(int* bsum, int nb){
  __shared__ int ls[256];
  int t=threadIdx.x;
  int v = (t<nb)? bsum[t]:0; ls[t]=v; __syncthreads();
  for(int off=1;off<256;off<<=1){
    int add = (t>=off)? ls[t-off]:0;
    __syncthreads();
    ls[t]+=add;
    __syncthreads();
  }
  if(t<nb) bsum[t] = ls[t]-v;   // exclusive
}
__global__ void k_scan_c(const int* indeg, const int* bsum, int* row_ptr, int N){
  __shared__ int ts[256];
  int b=blockIdx.x, t=threadIdx.x;
  int base=b*SCAN_CHUNK+t*8;
  int v[8]; int s=0;
  for(int j=0;j<8;j++){ int idx=base+j; v[j]=(idx<N)?indeg[idx]:0; s+=v[j]; }
  ts[t]=s; __syncthreads();
  for(int off=1;off<256;off<<=1){
    int add = (t>=off)? ts[t-off]:0;
    __syncthreads();
    ts[t]+=add;
    __syncthreads();
  }
  int excl = bsum[b] + ((t>0)? ts[t-1]:0);
  for(int j=0;j<8;j++){ int idx=base+j; if(idx<N) row_ptr[idx]=excl; excl+=v[j]; }
}

// ---------------- place edges into CSR (sorted by target position) ----------------
__global__ void k_place(const int* ei, const int* fl, const int* node_rank,
                        const int* ints, const int* row_ptr, int* fill,
                        int* edge_src, int E){
  int i = blockIdx.x*blockDim.x+threadIdx.x;
  int stride = gridDim.x*blockDim.x;
  for(int e=i;e<E;e+=stride){
    int s  = ei[e];
    int tg = ei[E+e];
    int p = ints[32+fl[tg]] + node_rank[tg];
    int slot = atomicAdd(&fill[p],1);
    edge_src[row_ptr[p]+slot] = s;
  }
}

// ---------------- out = c0 everywhere (level>=1 nodes overwritten later) ----------
__global__ void k_outc(float* out, const float* consts, int N){
  int i = blockIdx.x*blockDim.x+threadIdx.x;
  int stride = gridDim.x*blockDim.x;
  float c0 = consts[640];
  for(int j=i;j<N;j+=stride) out[j]=c0;
}

// ---------------- fused per-level: gather + GEMM(gi) + GRU + GEMM(t) + MLP -------
// smem floats (10016 total = 40064 B -> 4 blocks/CU):
//   region A @0 (5280): inpT[144][36]=5184 ; after GEMM1: hl[32][132]=4224, z1l@4224 [32][33]=1056,
//                       z2l@0 [32][33] (hl dead)
//   region B @5280 (4736): wl (w_ih 12x388=4656 | agg_w 16x132=2112 | w1 128x37=4736 | w2 32x37)
__global__ __launch_bounds__(256,4) void k_fused(
    const float* __restrict__ x, const int* __restrict__ node_list,
    const int* __restrict__ row_ptr, const int* __restrict__ indeg,
    const int* __restrict__ edge_src, const int* __restrict__ fl,
    float* __restrict__ tbuf,
    const float* __restrict__ w_ih, const float* __restrict__ b_ih,
    const float* __restrict__ agg_w, const float* __restrict__ agg_b,
    const float* __restrict__ w1,const float* __restrict__ b1,
    const float* __restrict__ w2,const float* __restrict__ b2,
    const float* __restrict__ w3,const float* __restrict__ b3,
    const float* __restrict__ consts, float* __restrict__ out,
    const int* __restrict__ ints, int l)
{
  __shared__ __align__(16) float smem[10016];
  float* inpT = smem;            // [144][36]
  float* hl   = smem;            // [32][132] alias (inpT dead after GEMM1)
  float* z1l  = smem + 4224;     // [32][33]
  float* z2l  = smem;            // [32][33] alias (hl dead)
  float* wl   = smem + 5280;

  int base = ints[32+l];
  int cnt  = ints[0+l];
  int tiles = (cnt+31)>>5;
  int tid = threadIdx.x;
  int tx = tid & 31;   // dim group: dims tx*4..tx*4+3
  int ty = tid >> 5;   // node group: nodes ty*4..ty*4+3
  int cg = tid & 7;    // gather: dim-quarter (16 floats = 4 float4)
  int nd = tid >> 3;   // gather: node slot 0..31

  // t_init fragment for this thread's gather columns
  float4 ti[4];
  {
    const float4* c4 = (const float4*)(consts+128);
    #pragma unroll
    for(int q=0;q<4;q++) ti[q] = c4[cg*4+q];
  }

  for(int tile = blockIdx.x; tile < tiles; tile += gridDim.x){
    int n0 = tile*32;

    // ---- gather msg via CSR: 8 threads per node, 16 dims each ----
    {
      float4 a[4];
      #pragma unroll
      for(int q=0;q<4;q++) a[q]=make_float4(0.f,0.f,0.f,0.f);
      int gi = n0 + nd;
      if(gi<cnt){
        int p = base+gi;
        int r0 = row_ptr[p];
        int deg = indeg[p];
        const float4* t4 = (const float4*)tbuf;
        for(int e=0;e<deg;e++){
          int s = edge_src[r0+e];
          int fls = fl[s];
          if(fls>=1 && fls<l){
            const float4* src = t4 + ((long long)s*32 + cg*4);
            #pragma unroll
            for(int q=0;q<4;q++){
              float4 v = src[q];
              a[q].x+=v.x; a[q].y+=v.y; a[q].z+=v.z; a[q].w+=v.w;
            }
          } else {
            #pragma unroll
            for(int q=0;q<4;q++){
              a[q].x+=ti[q].x; a[q].y+=ti[q].y; a[q].z+=ti[q].z; a[q].w+=ti[q].w;
            }
          }
        }
      }
      // write transposed: inpT[k][node], k = cg*16 + q*4 + r
      #pragma unroll
      for(int q=0;q<4;q++){
        int kbase = cg*16 + q*4;
        inpT[(kbase+0)*36 + nd] = a[q].x;
        inpT[(kbase+1)*36 + nd] = a[q].y;
        inpT[(kbase+2)*36 + nd] = a[q].z;
        inpT[(kbase+3)*36 + nd] = a[q].w;
      }
    }
    // ---- x into inpT rows 128..143 ----
    if(tid<128){
      int i = tid>>2, j = tid&3;
      int gi = n0+i;
      int vq = node_list[base + ((gi<cnt)?gi:0)];
      float4 xv = (gi<cnt)? ((const float4*)x)[vq*4+j] : make_float4(0.f,0.f,0.f,0.f);
      int kb = 128 + j*4;
      inpT[(kb+0)*36 + i] = xv.x;
      inpT[(kb+1)*36 + i] = xv.y;
      inpT[(kb+2)*36 + i] = xv.z;
      inpT[(kb+3)*36 + i] = xv.w;
    }
    __syncthreads();

    // ---- GEMM1: gi = W_ih @ [msg,x] + b_ih ----
    float ar[4][4], az[4][4], an[4][4];
    #pragma unroll
    for(int di=0;di<4;di++){
      float br = b_ih[tx*4+di], bz = b_ih[128+tx*4+di], bn = b_ih[256+tx*4+di];
      #pragma unroll
      for(int ni=0;ni<4;ni++){ ar[ni][di]=br; az[ni][di]=bz; an[ni][di]=bn; }
    }
    for(int k0=0;k0<DIN;k0+=12){
      for(int idx=tid; idx<4608; idx+=256){
        int g = idx/12, kk = idx - g*12;
        wl[kk*388+g] = w_ih[g*DIN + k0 + kk];
      }
      __syncthreads();
      #pragma unroll 4
      for(int kk=0;kk<12;kk++){
        float4 wr = *(const float4*)&wl[kk*388 + tx*4];
        float4 wz = *(const float4*)&wl[kk*388 + 128 + tx*4];
        float4 wn = *(const float4*)&wl[kk*388 + 256 + tx*4];
        float4 a4 = *(const float4*)&inpT[(k0+kk)*36 + ty*4];
        float avv[4]={a4.x,a4.y,a4.z,a4.w};
        float wrv[4]={wr.x,wr.y,wr.z,wr.w};
        float wzv[4]={wz.x,wz.y,wz.z,wz.w};
        float wnv[4]={wn.x,wn.y,wn.z,wn.w};
        #pragma unroll
        for(int ni=0;ni<4;ni++){
          #pragma unroll
          for(int di=0;di<4;di++){
            ar[ni][di] += avv[ni]*wrv[di];
            az[ni][di] += avv[ni]*wzv[di];
            an[ni][di] += avv[ni]*wnv[di];
          }
        }
      }
      __syncthreads();
    }

    // ---- GRU gates -> h_new into hl (aliases inpT; all inpT reads done) ----
    #pragma unroll
    for(int ni=0;ni<4;ni++){
      int i = ty*4+ni;
      float hv[4];
      #pragma unroll
      for(int di=0;di<4;di++){
        int d = tx*4+di;
        float r = sigmoidf_(ar[ni][di] + consts[256+d]);
        float z = sigmoidf_(az[ni][di] + consts[384+d]);
        float n = tanhf_(an[ni][di] + r*consts[512+d]);
        hv[di] = (1.f-z)*n + z*consts[d];
      }
      *(float4*)&hl[i*132 + tx*4] = make_float4(hv[0],hv[1],hv[2],hv[3]);
    }
    __syncthreads();

    // ---- GEMM2: t = agg_w @ h_new + agg_b ----
    float ac[4][4];
    #pragma unroll
    for(int di=0;di<4;di++){
      float b = agg_b[tx*4+di];
      #pragma unroll
      for(int ni=0;ni<4;ni++) ac[ni][di]=b;
    }
    for(int k0=0;k0<DHID;k0+=16){
      for(int idx=tid; idx<2048; idx+=256){
        int kk = idx&15, g = idx>>4;
        wl[kk*132+g] = agg_w[g*DHID + k0 + kk];
      }
      __syncthreads();
      #pragma unroll 4
      for(int kk=0;kk<16;kk++){
        float4 wv = *(const float4*)&wl[kk*132 + tx*4];
        int k = k0+kk;
        float avv[4] = { hl[(ty*4+0)*132+k], hl[(ty*4+1)*132+k],
                         hl[(ty*4+2)*132+k], hl[(ty*4+3)*132+k] };
        float wvv[4]={wv.x,wv.y,wv.z,wv.w};
        #pragma unroll
        for(int ni=0;ni<4;ni++){
          #pragma unroll
          for(int di=0;di<4;di++) ac[ni][di] += avv[ni]*wvv[di];
        }
      }
      __syncthreads();
    }
    #pragma unroll
    for(int ni=0;ni<4;ni++){
      int i = ty*4+ni; int gi = n0+i;
      if(gi<cnt){
        int v = node_list[base+gi];
        ((float4*)tbuf)[(long long)v*32+tx] = make_float4(ac[ni][0],ac[ni][1],ac[ni][2],ac[ni][3]);
      }
    }

    // ---- MLP from hl -> out ----
    for(int idx=tid; idx<4096; idx+=256){
      int j = idx>>7, k = idx&127;
      wl[k*37+j] = w1[idx];
    }
    __syncthreads();
    {
      int i = tid>>3;
      int jb = (tid&7)*4;
      float s[4];
      #pragma unroll
      for(int jj=0;jj<4;jj++) s[jj]=b1[jb+jj];
      for(int k=0;k<128;k++){
        float hv = hl[i*132+k];
        #pragma unroll
        for(int jj=0;jj<4;jj++) s[jj] += hv*wl[k*37+jb+jj];
      }
      #pragma unroll
      for(int jj=0;jj<4;jj++) z1l[i*33+jb+jj] = fmaxf(s[jj],0.f);
    }
    __syncthreads();
    for(int idx=tid; idx<1024; idx+=256){
      int j = idx>>5, k = idx&31;
      wl[k*37+j] = w2[idx];
    }
    __syncthreads();
    {
      int i = tid>>3;
      int jb = (tid&7)*4;
      float s[4];
      #pragma unroll
      for(int jj=0;jj<4;jj++) s[jj]=b2[jb+jj];
      for(int k=0;k<32;k++){
        float zv = z1l[i*33+k];
        #pragma unroll
        for(int jj=0;jj<4;jj++) s[jj] += zv*wl[k*37+jb+jj];
      }
      #pragma unroll
      for(int jj=0;jj<4;jj++) z2l[i*33+jb+jj] = fmaxf(s[jj],0.f);
    }
    __syncthreads();
    if(tid<32){
      int gi = n0+tid;
      if(gi<cnt){
        float s = b3[0];
        for(int k=0;k<32;k++) s += z2l[tid*33+k]*w3[k];
        out[node_list[base+gi]] = s;
      }
    }
    __syncthreads();   // protect LDS before next tile
  }
}

extern "C" void kernel_launch(void* const* d_in, const int* in_sizes, int n_in,
                              void* d_out, int out_size, void* d_ws, size_t ws_size,
                              hipStream_t stream){
  const float* x     = (const float*)d_in[0];
  const int*   ei    = (const int*)  d_in[1];
  const int*   fl    = (const int*)  d_in[2];
  const float* emd_w = (const float*)d_in[4];
  const float* emd_b = (const float*)d_in[5];
  const float* agg_w = (const float*)d_in[6];
  const float* agg_b = (const float*)d_in[7];
  const float* w_ih  = (const float*)d_in[8];
  const float* w_hh  = (const float*)d_in[9];
  const float* b_ih  = (const float*)d_in[10];
  const float* b_hh  = (const float*)d_in[11];
  const float* w1    = (const float*)d_in[12];
  const float* b1    = (const float*)d_in[13];
  const float* w2    = (const float*)d_in[14];
  const float* b2    = (const float*)d_in[15];
  const float* w3    = (const float*)d_in[16];
  const float* b3    = (const float*)d_in[17];
  float* out = (float*)d_out;

  int N = in_sizes[2];
  int E = in_sizes[1]/2;
  int nb = (N + SCAN_CHUNK - 1)/SCAN_CHUNK;

  char* ws = (char*)d_ws;
  float* consts   = (float*)ws;                    // 4 KiB
  int*   ints     = (int*)(ws + 4096);             // 4 KiB
  int*   node_list= (int*)(ws + 8192);
  int*   node_rank= node_list + N;
  int*   indeg    = node_rank + N;
  int*   row_ptr  = indeg + N;
  int*   fill     = row_ptr + N;
  int*   bsum     = fill + N;                      // up to 1024 block sums
  int*   edge_src = bsum + 1024;                   // E ints
  size_t off = 8192 + ((size_t)5*N + 1024 + (size_t)E)*4;
  off = (off + 255) & ~(size_t)255;
  float* tbuf = (float*)(ws + off);                // N*128 floats, NEVER pre-initialized
  size_t need = off + (size_t)N*128*4;
  if(ws_size < need) return;

  k_zero0  <<<512,256,0,stream>>>(ints, indeg, fill, N);
  k_init   <<<1,128,0,stream>>>(emd_w,emd_b,agg_w,agg_b,w_hh,b_hh,w1,b1,w2,b2,w3,b3,consts);
  k_count  <<<512,256,0,stream>>>(fl,N,ints);
  k_prefix <<<1,1,0,stream>>>(ints);
  k_build  <<<512,256,0,stream>>>(fl,N,ints,node_list,node_rank);
  k_indeg  <<<1024,256,0,stream>>>(ei,fl,node_rank,ints,indeg,E);
  k_scan_a <<<nb,256,0,stream>>>(indeg,bsum,N);
  k_scan_b <<<1,256,0,stream>>>(bsum,nb);
  k_scan_c <<<nb,256,0,stream>>>(indeg,bsum,row_ptr,N);
  k_place  <<<1024,256,0,stream>>>(ei,fl,node_rank,ints,row_ptr,fill,edge_src,E);
  k_outc   <<<512,256,0,stream>>>(out,consts,N);
  for(int l=1;l<NLEV;l++){
    k_fused<<<512,256,0,stream>>>(x,node_list,row_ptr,indeg,edge_src,fl,tbuf,
                                  w_ih,b_ih,agg_w,agg_b,
                                  w1,b1,w2,b2,w3,b3,consts,out,ints,l);
  }
}